// Round 17
// baseline (253.986 us; speedup 1.0000x reference)
//
#include <hip/hip_runtime.h>
#include <hip/hip_bf16.h>

#define B_  2
#define L_  2048
#define D_  1024
#define H_  16
#define HD_ 64

typedef __bf16 bf16x8 __attribute__((ext_vector_type(8)));
typedef float  f32x4  __attribute__((ext_vector_type(4)));
using bf16_t = __hip_bfloat16;
typedef unsigned int u32;
typedef unsigned long long u64;

static __device__ __forceinline__ f32x4 mfma16(bf16x8 a, bf16x8 b, f32x4 c) {
    return __builtin_amdgcn_mfma_f32_16x16x32_bf16(a, b, c, 0, 0, 0);
}

// async global->LDS, 16B per lane; LDS dest = wave-uniform base + lane*16
static __device__ __forceinline__ void gl16(const bf16_t* g, bf16_t* l) {
    __builtin_amdgcn_global_load_lds(
        (const __attribute__((address_space(1))) unsigned int*)g,
        (__attribute__((address_space(3))) unsigned int*)l, 16, 0, 0);
}

// packed f32x2 -> bf16x2 (lo in low half)
static __device__ __forceinline__ u32 cvtpk(float lo, float hi) {
    u32 r;
    asm("v_cvt_pk_bf16_f32 %0, %1, %2" : "=v"(r) : "v"(lo), "v"(hi));
    return r;
}

// ---- prep: z<4 -> transpose W[k][n] to bf16 Wt[n][k]; z>=4 -> convert x to bf16 ----
__global__ __launch_bounds__(256) void k_prep(
        const float* __restrict__ x,
        const float* __restrict__ w0, const float* __restrict__ w1,
        const float* __restrict__ w2, const float* __restrict__ w3,
        bf16_t* __restrict__ xb,
        bf16_t* __restrict__ t0, bf16_t* __restrict__ t1,
        bf16_t* __restrict__ t2, bf16_t* __restrict__ t3) {
    __shared__ bf16_t tile[64][65];
    int z = blockIdx.z;
    int t = threadIdx.x;
    if (z >= 4) {
        int slice = z - 4;                              // 0..7
        int lin = blockIdx.y * 16 + blockIdx.x;         // 0..255
        int idx = (slice * 256 + lin) * 256 + t;        // 0..524287
        const float4* p = (const float4*)x + (size_t)idx * 2;
        float4 a = p[0], b = p[1];
        union { bf16_t h[8]; bf16x8 v; } u;
        u.h[0] = __float2bfloat16(a.x); u.h[1] = __float2bfloat16(a.y);
        u.h[2] = __float2bfloat16(a.z); u.h[3] = __float2bfloat16(a.w);
        u.h[4] = __float2bfloat16(b.x); u.h[5] = __float2bfloat16(b.y);
        u.h[6] = __float2bfloat16(b.z); u.h[7] = __float2bfloat16(b.w);
        *(bf16x8*)(xb + (size_t)idx * 8) = u.v;
        return;
    }
    const float* w = (z == 0) ? w0 : (z == 1) ? w1 : (z == 2) ? w2 : w3;
    bf16_t* wt     = (z == 0) ? t0 : (z == 1) ? t1 : (z == 2) ? t2 : t3;
    int kb = blockIdx.x * 64, nb = blockIdx.y * 64;
    int r  = t >> 4, c4 = (t & 15) * 4;
    #pragma unroll
    for (int it = 0; it < 4; ++it) {
        int kr = r + it * 16;
        float4 v = *(const float4*)&w[(size_t)(kb + kr) * D_ + nb + c4];
        tile[kr][c4 + 0] = __float2bfloat16(v.x);
        tile[kr][c4 + 1] = __float2bfloat16(v.y);
        tile[kr][c4 + 2] = __float2bfloat16(v.z);
        tile[kr][c4 + 3] = __float2bfloat16(v.w);
    }
    __syncthreads();
    #pragma unroll
    for (int it = 0; it < 4; ++it) {
        int nr = r + it * 16;
        union { bf16_t h[4]; u64 u; } o;
        o.h[0] = tile[c4 + 0][nr];
        o.h[1] = tile[c4 + 1][nr];
        o.h[2] = tile[c4 + 2][nr];
        o.h[3] = tile[c4 + 3][nr];
        *(u64*)&wt[(size_t)(nb + nr) * D_ + kb + c4] = o.u;
    }
}

// ---- merged QKV GEMM: z=0 -> Q [B,H,L,HD], z=1 -> K [B,H,L,HD], z=2 -> V^T [B,H,HD,L]
__global__ __launch_bounds__(256, 3) void k_gemm_qkv(
        const bf16_t* __restrict__ A,
        const bf16_t* __restrict__ Wq, const bf16_t* __restrict__ Wk, const bf16_t* __restrict__ Wv,
        const float* __restrict__ bq, const float* __restrict__ bk, const float* __restrict__ bv,
        bf16_t* __restrict__ Qo, bf16_t* __restrict__ Ko, bf16_t* __restrict__ Vo) {
    __shared__ __align__(16) bf16_t Al[128][32];
    __shared__ __align__(16) bf16_t Bl[128][32];
    const int K = D_;
    int z = blockIdx.z;
    const bf16_t* Wt = (z == 0) ? Wq : (z == 1) ? Wk : Wv;
    const float* bias = (z == 0) ? bq : (z == 1) ? bk : bv;
    bf16_t* outp      = (z == 0) ? Qo : (z == 1) ? Ko : Vo;
    int tid = threadIdx.x, lane = tid & 63, wid = tid >> 6;
    int m0 = blockIdx.y * 128, n0 = blockIdx.x * 128;
    int wm = (wid >> 1) * 64, wn = (wid & 1) * 64;
    int r16 = lane & 15, g = lane >> 4;
    int lrow = lane >> 2, lcol = (lane & 3) * 8;
    f32x4 acc[4][4] = {};
    for (int kb = 0; kb < K; kb += 32) {
        __syncthreads();
        gl16(&A [(size_t)(m0 + wid * 32 + lrow) * K + kb + lcol],      &Al[wid * 32][0]);
        gl16(&A [(size_t)(m0 + wid * 32 + 16 + lrow) * K + kb + lcol], &Al[wid * 32 + 16][0]);
        gl16(&Wt[(size_t)(n0 + wid * 32 + lrow) * K + kb + lcol],      &Bl[wid * 32][0]);
        gl16(&Wt[(size_t)(n0 + wid * 32 + 16 + lrow) * K + kb + lcol], &Bl[wid * 32 + 16][0]);
        __syncthreads();
        bf16x8 af[4], bfr[4];
        #pragma unroll
        for (int i = 0; i < 4; ++i) af[i]  = *(const bf16x8*)&Al[wm + i * 16 + r16][g * 8];
        #pragma unroll
        for (int j = 0; j < 4; ++j) bfr[j] = *(const bf16x8*)&Bl[wn + j * 16 + r16][g * 8];
        #pragma unroll
        for (int i = 0; i < 4; ++i)
            #pragma unroll
            for (int j = 0; j < 4; ++j)
                acc[i][j] = mfma16(af[i], bfr[j], acc[i][j]);
    }
    if (z == 2) {
        #pragma unroll
        for (int i = 0; i < 4; ++i)
            #pragma unroll
            for (int j = 0; j < 4; ++j) {
                int n = n0 + wn + j * 16 + r16;
                float bv2 = bias[n];
                int h = n >> 6, hd = n & 63;
                int m = m0 + wm + i * 16 + g * 4;
                int bb = m >> 11, l0 = m & (L_ - 1);
                u32 lo = cvtpk(acc[i][j][0] + bv2, acc[i][j][1] + bv2);
                u32 hi = cvtpk(acc[i][j][2] + bv2, acc[i][j][3] + bv2);
                u64 pk = ((u64)hi << 32) | lo;
                *(u64*)&Vo[(((size_t)(bb * H_ + h)) * HD_ + hd) * L_ + l0] = pk;
            }
    } else {
        #pragma unroll
        for (int i = 0; i < 4; ++i) {
            #pragma unroll
            for (int j = 0; j < 4; ++j) {
                int n = n0 + wn + j * 16 + r16;
                float bv2 = bias[n];
                int h = n >> 6, hd = n & 63;
                #pragma unroll
                for (int e = 0; e < 4; ++e) {
                    int m = m0 + wm + i * 16 + g * 4 + e;
                    float v = acc[i][j][e] + bv2;
                    int bb = m >> 11, l = m & (L_ - 1);
                    outp[(((size_t)(bb * H_ + h)) * L_ + l) * HD_ + hd] = __float2bfloat16(v);
                }
            }
        }
    }
}

// ---- attention phase 1: R15-exact. ctx + invz out; zero-fill prologue ----
__global__ __launch_bounds__(256, 4) void k_attn_p1(const bf16_t* __restrict__ Q,
                                                    const bf16_t* __restrict__ Kb,
                                                    const bf16_t* __restrict__ VT,
                                                    bf16_t* __restrict__ ctx,
                                                    float* __restrict__ attn,
                                                    float* __restrict__ invzbuf) {
    __shared__ __align__(16) bf16_t K_lds[2][64][64];
    __shared__ __align__(16) bf16_t V_lds[2][64][64];
    int tid = threadIdx.x, lane = tid & 63, wid = tid >> 6;
    int bid = blockIdx.x;
    int r   = bid >> 3;                    // 0..127
    int jj  = r & 31, s = r >> 5;          // CU-slot j, head-group s
    int bh  = (bid & 7) + 8 * s;           // 4 heads per XCD
    int j2  = (jj + ((s >> 1) << 4)) & 31;
    int qt  = (s & 1) ? (31 - j2) : j2;    // balanced involution
    int b = bh >> 4, h = bh & 15;
    int qb = qt * 64;
    const int diag = qt;
    const bf16_t* Qh = Q  + (size_t)bh * L_ * HD_;
    const bf16_t* Kh = Kb + (size_t)bh * L_ * HD_;
    const bf16_t* Vh = VT + (size_t)bh * HD_ * L_;
    int r16 = lane & 15, g = lane >> 4;
    const float scale2 = 0.125f * 1.44269504088896340736f;
    const float clamp2 = 50.0f * 1.44269504088896340736f;
    int qrow0 = qb + wid * 16;
    int qrow  = qrow0 + r16;

    // zero-fill upper triangle FIRST: fire-and-forget NT stores
    {
        int zs = qb + 64;
        f32x4 z4 = {0.f, 0.f, 0.f, 0.f};
        for (int rr = 0; rr < 16; ++rr) {
            float* rowp = attn + ((size_t)bh * L_ + qrow0 + rr) * L_;
            for (int c = zs + lane * 4; c < L_; c += 256)
                __builtin_nontemporal_store(z4, (f32x4*)&rowp[c]);
        }
    }

    bf16x8 q0 = *(const bf16x8*)&Qh[(size_t)qrow * HD_ + g * 8];
    bf16x8 q1 = *(const bf16x8*)&Qh[(size_t)qrow * HD_ + 32 + g * 8];

    int srow = lane >> 3, sunit = ((lane & 7) ^ (lane >> 3)) * 8;
    auto STAGE_K = [&](int kt1, int nxt) {
        #pragma unroll
        for (int i = 0; i < 2; ++i) {
            int cb = wid * 16 + i * 8;
            gl16(&Kh[(size_t)(kt1 * 64 + cb + srow) * HD_ + sunit], &K_lds[nxt][cb][0]);
        }
    };
    auto STAGE_V = [&](int kt1, int nxt) {
        #pragma unroll
        for (int i = 0; i < 2; ++i) {
            int cb = wid * 16 + i * 8;
            gl16(&Vh[(size_t)(cb + srow) * L_ + kt1 * 64 + sunit], &V_lds[nxt][cb][0]);
        }
    };

    f32x4 ctxa[4] = {};
    float zsum = 0.f;
    int rx = r16 & 7;

    STAGE_K(0, 0); STAGE_V(0, 0);
    int cur = 0;
    for (int kt = 0; kt <= diag; ++kt) {
        __syncthreads();
        int nxt = cur ^ 1;
        if (kt < diag) { STAGE_K(kt + 1, nxt); STAGE_V(kt + 1, nxt); }
        int kb = kt * 64;
        #pragma unroll
        for (int sub = 0; sub < 2; ++sub) {
            f32x4 sa[2];
            #pragma unroll
            for (int sp = 0; sp < 2; ++sp) {
                int krow = sub * 32 + sp * 16 + r16;
                bf16x8 kf0 = *(const bf16x8*)&K_lds[cur][krow][(g ^ rx) * 8];
                bf16x8 kf1 = *(const bf16x8*)&K_lds[cur][krow][((4 + g) ^ rx) * 8];
                f32x4 zz = {};
                sa[sp] = mfma16(kf1, q1, mfma16(kf0, q0, zz));
            }
            int kb2 = kb + sub * 32;
            u32 dw[2][2];
            #pragma unroll
            for (int sp = 0; sp < 2; ++sp) {
                float ev[4];
                #pragma unroll
                for (int e = 0; e < 4; ++e) {
                    int key = kb2 + sp * 16 + g * 4 + e;
                    float sc = fminf(fmaxf(sa[sp][e] * scale2, -clamp2), clamp2);
                    ev[e] = (key > qrow) ? 0.f : exp2f(sc);
                    zsum += ev[e];
                }
                dw[sp][0] = cvtpk(ev[0], ev[1]);
                dw[sp][1] = cvtpk(ev[2], ev[3]);
            }
            union { u32 u[4]; bf16x8 v; } pa;
            pa.u[0] = dw[0][0]; pa.u[1] = dw[0][1];
            pa.u[2] = dw[1][0]; pa.u[3] = dw[1][1];
            #pragma unroll
            for (int t = 0; t < 4; ++t) {
                int vrow = t * 16 + r16;
                int u0 = ((sub * 4 + (g >> 1)) ^ rx) * 8 + (g & 1) * 4;
                int u1 = ((sub * 4 + 2 + (g >> 1)) ^ rx) * 8 + (g & 1) * 4;
                union { u64 d[2]; bf16x8 v; } vf;
                vf.d[0] = *(const u64*)&V_lds[cur][vrow][u0];
                vf.d[1] = *(const u64*)&V_lds[cur][vrow][u1];
                ctxa[t] = mfma16(pa.v, vf.v, ctxa[t]);
            }
        }
        cur = nxt;
    }

    float v = zsum;
    v += __shfl_xor(v, 16);
    v += __shfl_xor(v, 32);
    float invz = 1.f / v;
    if (g == 0) invzbuf[(size_t)bh * L_ + qrow] = invz;

    // normalized context -> ctx [B, L, D] bf16 (PV D: row=g*4+e=q, col=r16=hd)
    #pragma unroll
    for (int e = 0; e < 4; ++e) {
        float izq = __shfl(invz, g * 4 + e);
        int qr = qrow0 + g * 4 + e;
        #pragma unroll
        for (int t = 0; t < 4; ++t)
            ctx[((size_t)b * L_ + qr) * D_ + h * HD_ + t * 16 + r16] =
                __float2bfloat16(ctxa[t][e] * izq);
    }
}

// ---- merged writer + O-GEMM (ordinary launch; heterogeneous blocks) ----
// bid < 512: o-projection 128x64 tile (MFMA-bound, depends only on ctx).
// bid >= 512: barrier-free streaming writer (direct-global K from L2, NT stores,
// invz from buffer, balanced map). Co-resident -> o hides under store stream.
__global__ __launch_bounds__(256, 4) void k_wr_o(
        const bf16_t* __restrict__ Q, const bf16_t* __restrict__ Kb,
        const float* __restrict__ invzbuf, float* __restrict__ attn,
        const bf16_t* __restrict__ ctxb, const bf16_t* __restrict__ Wo,
        const float* __restrict__ bo, float* __restrict__ outp) {
    __shared__ __align__(16) bf16_t Al[128][32];
    __shared__ __align__(16) bf16_t Bl[64][32];
    int tid = threadIdx.x, lane = tid & 63, wid = tid >> 6;
    int bid = blockIdx.x;
    int r16 = lane & 15, g = lane >> 4;

    if (bid < 512) {
        // ---- o-projection GEMM, 128x64 tile ----
        const int K = D_;
        int m0 = (bid >> 4) * 128, n0 = (bid & 15) * 64;
        int wm = (wid >> 1) * 64, wn = (wid & 1) * 32;
        int lrow = lane >> 2, lcol = (lane & 3) * 8;
        f32x4 acc[4][2] = {};
        for (int kb = 0; kb < K; kb += 32) {
            __syncthreads();
            gl16(&ctxb[(size_t)(m0 + wid * 32 + lrow) * K + kb + lcol],      &Al[wid * 32][0]);
            gl16(&ctxb[(size_t)(m0 + wid * 32 + 16 + lrow) * K + kb + lcol], &Al[wid * 32 + 16][0]);
            gl16(&Wo  [(size_t)(n0 + wid * 16 + lrow) * K + kb + lcol],      &Bl[wid * 16][0]);
            __syncthreads();
            bf16x8 af[4], bfr[2];
            #pragma unroll
            for (int i = 0; i < 4; ++i) af[i]  = *(const bf16x8*)&Al[wm + i * 16 + r16][g * 8];
            #pragma unroll
            for (int j = 0; j < 2; ++j) bfr[j] = *(const bf16x8*)&Bl[wn + j * 16 + r16][g * 8];
            #pragma unroll
            for (int i = 0; i < 4; ++i)
                #pragma unroll
                for (int j = 0; j < 2; ++j)
                    acc[i][j] = mfma16(af[i], bfr[j], acc[i][j]);
        }
        #pragma unroll
        for (int i = 0; i < 4; ++i)
            #pragma unroll
            for (int j = 0; j < 2; ++j) {
                int n = n0 + wn + j * 16 + r16;
                float bv = bo[n];
                #pragma unroll
                for (int e = 0; e < 4; ++e) {
                    int m = m0 + wm + i * 16 + g * 4 + e;
                    outp[(size_t)m * D_ + n] = acc[i][j][e] + bv;
                }
            }
        return;
    }

    // ---- writer: barrier-free streaming ----
    int wbid = bid - 512;
    int r   = wbid >> 3;                   // 0..127
    int jj  = r & 31, s = r >> 5;
    int bh  = (wbid & 7) + 8 * s;          // 4 heads per XCD
    int j2  = (jj + ((s >> 1) << 4)) & 31;
    int qt  = (s & 1) ? (31 - j2) : j2;    // balanced involution
    int qb = qt * 64;
    const int diag = qt;
    const bf16_t* Qh = Q  + (size_t)bh * L_ * HD_;
    const bf16_t* Kh = Kb + (size_t)bh * L_ * HD_;
    const float scale2 = 0.125f * 1.44269504088896340736f;
    const float clamp2 = 50.0f * 1.44269504088896340736f;
    int qrow0 = qb + wid * 16;
    int qrow  = qrow0 + r16;

    float invz = invzbuf[(size_t)bh * L_ + qrow];
    bf16x8 q0 = *(const bf16x8*)&Qh[(size_t)qrow * HD_ + g * 8];
    bf16x8 q1 = *(const bf16x8*)&Qh[(size_t)qrow * HD_ + 32 + g * 8];

    for (int kt = 0; kt <= diag; ++kt) {
        #pragma unroll
        for (int sub = 0; sub < 2; ++sub) {
            int krow0 = kt * 64 + sub * 32;
            #pragma unroll
            for (int sp = 0; sp < 2; ++sp) {
                const bf16_t* kp = &Kh[(size_t)(krow0 + sp * 16 + r16) * HD_ + g * 8];
                bf16x8 kf0 = *(const bf16x8*)kp;
                bf16x8 kf1 = *(const bf16x8*)(kp + 32);
                f32x4 zz = {};
                f32x4 sa = mfma16(kf1, q1, mfma16(kf0, q0, zz));
                int cb = krow0 + sp * 16 + g * 4;
                f32x4 fv;
                #pragma unroll
                for (int e = 0; e < 4; ++e) {
                    int key = cb + e;
                    float sc = fminf(fmaxf(sa[e] * scale2, -clamp2), clamp2);
                    fv[e] = (key > qrow) ? 0.f : exp2f(sc) * invz;
                }
                __builtin_nontemporal_store(fv,
                    (f32x4*)&attn[((size_t)bh * L_ + qrow) * L_ + cb]);
            }
        }
    }
}

extern "C" void kernel_launch(void* const* d_in, const int* in_sizes, int n_in,
                              void* d_out, int out_size, void* d_ws, size_t ws_size,
                              hipStream_t stream) {
    const float* x  = (const float*)d_in[0];
    const float* wq = (const float*)d_in[1];
    const float* bq = (const float*)d_in[2];
    const float* wk = (const float*)d_in[3];
    const float* bk = (const float*)d_in[4];
    const float* wv = (const float*)d_in[5];
    const float* bv = (const float*)d_in[6];
    const float* wo = (const float*)d_in[7];
    const float* bo = (const float*)d_in[8];

    char* ws = (char*)d_ws;
    bf16_t* xb   = (bf16_t*)(ws);
    bf16_t* wqt  = (bf16_t*)(ws + ( 8u << 20));
    bf16_t* wkt  = (bf16_t*)(ws + (10u << 20));
    bf16_t* wvt  = (bf16_t*)(ws + (12u << 20));
    bf16_t* wot  = (bf16_t*)(ws + (14u << 20));
    bf16_t* Qb   = (bf16_t*)(ws + (16u << 20));
    bf16_t* Kbuf = (bf16_t*)(ws + (24u << 20));
    bf16_t* VTb  = (bf16_t*)(ws + (32u << 20));
    bf16_t* ctxb = (bf16_t*)(ws + (40u << 20));
    float*  invzbuf = (float*)(ws + (52u << 20));

    float* out  = (float*)d_out;
    float* attn = out + (size_t)B_ * L_ * D_;

    dim3 gp(16, 16, 12);
    k_prep<<<gp, 256, 0, stream>>>(x, wq, wk, wv, wo, xb, wqt, wkt, wvt, wot);

    dim3 g3(D_ / 128, (B_ * L_) / 128, 3);
    k_gemm_qkv<<<g3, 256, 0, stream>>>(xb, wqt, wkt, wvt, bq, bk, bv, Qb, Kbuf, VTb);

    k_attn_p1<<<1024, 256, 0, stream>>>(Qb, Kbuf, VTb, ctxb, attn, invzbuf);

    k_wr_o<<<1536, 256, 0, stream>>>(Qb, Kbuf, invzbuf, attn, ctxb, wot, bo, out);
}

// Round 18
// 220.848 us; speedup vs baseline: 1.1500x; 1.1500x over previous
//
#include <hip/hip_runtime.h>
#include <hip/hip_bf16.h>

#define B_  2
#define L_  2048
#define D_  1024
#define H_  16
#define HD_ 64

typedef __bf16 bf16x8 __attribute__((ext_vector_type(8)));
typedef float  f32x4  __attribute__((ext_vector_type(4)));
using bf16_t = __hip_bfloat16;
typedef unsigned int u32;
typedef unsigned long long u64;

static __device__ __forceinline__ f32x4 mfma16(bf16x8 a, bf16x8 b, f32x4 c) {
    return __builtin_amdgcn_mfma_f32_16x16x32_bf16(a, b, c, 0, 0, 0);
}

// async global->LDS, 16B per lane; LDS dest = wave-uniform base + lane*16
static __device__ __forceinline__ void gl16(const bf16_t* g, bf16_t* l) {
    __builtin_amdgcn_global_load_lds(
        (const __attribute__((address_space(1))) unsigned int*)g,
        (__attribute__((address_space(3))) unsigned int*)l, 16, 0, 0);
}

// packed f32x2 -> bf16x2 (lo in low half)
static __device__ __forceinline__ u32 cvtpk(float lo, float hi) {
    u32 r;
    asm("v_cvt_pk_bf16_f32 %0, %1, %2" : "=v"(r) : "v"(lo), "v"(hi));
    return r;
}

// ---- prep: z<4 -> transpose W[k][n] to bf16 Wt[n][k]; z>=4 -> convert x to bf16 ----
__global__ __launch_bounds__(256) void k_prep(
        const float* __restrict__ x,
        const float* __restrict__ w0, const float* __restrict__ w1,
        const float* __restrict__ w2, const float* __restrict__ w3,
        bf16_t* __restrict__ xb,
        bf16_t* __restrict__ t0, bf16_t* __restrict__ t1,
        bf16_t* __restrict__ t2, bf16_t* __restrict__ t3) {
    __shared__ bf16_t tile[64][65];
    int z = blockIdx.z;
    int t = threadIdx.x;
    if (z >= 4) {
        int slice = z - 4;                              // 0..7
        int lin = blockIdx.y * 16 + blockIdx.x;         // 0..255
        int idx = (slice * 256 + lin) * 256 + t;        // 0..524287
        const float4* p = (const float4*)x + (size_t)idx * 2;
        float4 a = p[0], b = p[1];
        union { bf16_t h[8]; bf16x8 v; } u;
        u.h[0] = __float2bfloat16(a.x); u.h[1] = __float2bfloat16(a.y);
        u.h[2] = __float2bfloat16(a.z); u.h[3] = __float2bfloat16(a.w);
        u.h[4] = __float2bfloat16(b.x); u.h[5] = __float2bfloat16(b.y);
        u.h[6] = __float2bfloat16(b.z); u.h[7] = __float2bfloat16(b.w);
        *(bf16x8*)(xb + (size_t)idx * 8) = u.v;
        return;
    }
    const float* w = (z == 0) ? w0 : (z == 1) ? w1 : (z == 2) ? w2 : w3;
    bf16_t* wt     = (z == 0) ? t0 : (z == 1) ? t1 : (z == 2) ? t2 : t3;
    int kb = blockIdx.x * 64, nb = blockIdx.y * 64;
    int r  = t >> 4, c4 = (t & 15) * 4;
    #pragma unroll
    for (int it = 0; it < 4; ++it) {
        int kr = r + it * 16;
        float4 v = *(const float4*)&w[(size_t)(kb + kr) * D_ + nb + c4];
        tile[kr][c4 + 0] = __float2bfloat16(v.x);
        tile[kr][c4 + 1] = __float2bfloat16(v.y);
        tile[kr][c4 + 2] = __float2bfloat16(v.z);
        tile[kr][c4 + 3] = __float2bfloat16(v.w);
    }
    __syncthreads();
    #pragma unroll
    for (int it = 0; it < 4; ++it) {
        int nr = r + it * 16;
        union { bf16_t h[4]; u64 u; } o;
        o.h[0] = tile[c4 + 0][nr];
        o.h[1] = tile[c4 + 1][nr];
        o.h[2] = tile[c4 + 2][nr];
        o.h[3] = tile[c4 + 3][nr];
        *(u64*)&wt[(size_t)(nb + nr) * D_ + kb + c4] = o.u;
    }
}

// ---- merged QKV GEMM: z=0 -> Q [B,H,L,HD], z=1 -> K [B,H,L,HD], z=2 -> V^T [B,H,HD,L]
__global__ __launch_bounds__(256, 3) void k_gemm_qkv(
        const bf16_t* __restrict__ A,
        const bf16_t* __restrict__ Wq, const bf16_t* __restrict__ Wk, const bf16_t* __restrict__ Wv,
        const float* __restrict__ bq, const float* __restrict__ bk, const float* __restrict__ bv,
        bf16_t* __restrict__ Qo, bf16_t* __restrict__ Ko, bf16_t* __restrict__ Vo) {
    __shared__ __align__(16) bf16_t Al[128][32];
    __shared__ __align__(16) bf16_t Bl[128][32];
    const int K = D_;
    int z = blockIdx.z;
    const bf16_t* Wt = (z == 0) ? Wq : (z == 1) ? Wk : Wv;
    const float* bias = (z == 0) ? bq : (z == 1) ? bk : bv;
    bf16_t* outp      = (z == 0) ? Qo : (z == 1) ? Ko : Vo;
    int tid = threadIdx.x, lane = tid & 63, wid = tid >> 6;
    int m0 = blockIdx.y * 128, n0 = blockIdx.x * 128;
    int wm = (wid >> 1) * 64, wn = (wid & 1) * 64;
    int r16 = lane & 15, g = lane >> 4;
    int lrow = lane >> 2, lcol = (lane & 3) * 8;
    f32x4 acc[4][4] = {};
    for (int kb = 0; kb < K; kb += 32) {
        __syncthreads();
        gl16(&A [(size_t)(m0 + wid * 32 + lrow) * K + kb + lcol],      &Al[wid * 32][0]);
        gl16(&A [(size_t)(m0 + wid * 32 + 16 + lrow) * K + kb + lcol], &Al[wid * 32 + 16][0]);
        gl16(&Wt[(size_t)(n0 + wid * 32 + lrow) * K + kb + lcol],      &Bl[wid * 32][0]);
        gl16(&Wt[(size_t)(n0 + wid * 32 + 16 + lrow) * K + kb + lcol], &Bl[wid * 32 + 16][0]);
        __syncthreads();
        bf16x8 af[4], bfr[4];
        #pragma unroll
        for (int i = 0; i < 4; ++i) af[i]  = *(const bf16x8*)&Al[wm + i * 16 + r16][g * 8];
        #pragma unroll
        for (int j = 0; j < 4; ++j) bfr[j] = *(const bf16x8*)&Bl[wn + j * 16 + r16][g * 8];
        #pragma unroll
        for (int i = 0; i < 4; ++i)
            #pragma unroll
            for (int j = 0; j < 4; ++j)
                acc[i][j] = mfma16(af[i], bfr[j], acc[i][j]);
    }
    if (z == 2) {
        #pragma unroll
        for (int i = 0; i < 4; ++i)
            #pragma unroll
            for (int j = 0; j < 4; ++j) {
                int n = n0 + wn + j * 16 + r16;
                float bv2 = bias[n];
                int h = n >> 6, hd = n & 63;
                int m = m0 + wm + i * 16 + g * 4;
                int bb = m >> 11, l0 = m & (L_ - 1);
                u32 lo = cvtpk(acc[i][j][0] + bv2, acc[i][j][1] + bv2);
                u32 hi = cvtpk(acc[i][j][2] + bv2, acc[i][j][3] + bv2);
                u64 pk = ((u64)hi << 32) | lo;
                *(u64*)&Vo[(((size_t)(bb * H_ + h)) * HD_ + hd) * L_ + l0] = pk;
            }
    } else {
        #pragma unroll
        for (int i = 0; i < 4; ++i) {
            #pragma unroll
            for (int j = 0; j < 4; ++j) {
                int n = n0 + wn + j * 16 + r16;
                float bv2 = bias[n];
                int h = n >> 6, hd = n & 63;
                #pragma unroll
                for (int e = 0; e < 4; ++e) {
                    int m = m0 + wm + i * 16 + g * 4 + e;
                    float v = acc[i][j][e] + bv2;
                    int bb = m >> 11, l = m & (L_ - 1);
                    outp[(((size_t)(bb * H_ + h)) * L_ + l) * HD_ + hd] = __float2bfloat16(v);
                }
            }
        }
    }
}

// ---- O-projection GEMM, 128x64 tiles ----
__global__ __launch_bounds__(256, 2) void k_gemm_o(const bf16_t* __restrict__ A,
                                                   const bf16_t* __restrict__ Wt,
                                                   const float* __restrict__ bias,
                                                   float* __restrict__ outp) {
    __shared__ __align__(16) bf16_t Al[128][32];
    __shared__ __align__(16) bf16_t Bl[64][32];
    const int K = D_;
    int tid = threadIdx.x, lane = tid & 63, wid = tid >> 6;
    int m0 = blockIdx.y * 128, n0 = blockIdx.x * 64;
    int wm = (wid >> 1) * 64, wn = (wid & 1) * 32;
    int r16 = lane & 15, g = lane >> 4;
    int lrow = lane >> 2, lcol = (lane & 3) * 8;
    f32x4 acc[4][2] = {};
    for (int kb = 0; kb < K; kb += 32) {
        __syncthreads();
        gl16(&A [(size_t)(m0 + wid * 32 + lrow) * K + kb + lcol],      &Al[wid * 32][0]);
        gl16(&A [(size_t)(m0 + wid * 32 + 16 + lrow) * K + kb + lcol], &Al[wid * 32 + 16][0]);
        gl16(&Wt[(size_t)(n0 + wid * 16 + lrow) * K + kb + lcol],      &Bl[wid * 16][0]);
        __syncthreads();
        bf16x8 af[4], bfr[2];
        #pragma unroll
        for (int i = 0; i < 4; ++i) af[i]  = *(const bf16x8*)&Al[wm + i * 16 + r16][g * 8];
        #pragma unroll
        for (int j = 0; j < 2; ++j) bfr[j] = *(const bf16x8*)&Bl[wn + j * 16 + r16][g * 8];
        #pragma unroll
        for (int i = 0; i < 4; ++i)
            #pragma unroll
            for (int j = 0; j < 2; ++j)
                acc[i][j] = mfma16(af[i], bfr[j], acc[i][j]);
    }
    #pragma unroll
    for (int i = 0; i < 4; ++i)
        #pragma unroll
        for (int j = 0; j < 2; ++j) {
            int n = n0 + wn + j * 16 + r16;
            float bv = bias[n];
            #pragma unroll
            for (int e = 0; e < 4; ++e) {
                int m = m0 + wm + i * 16 + g * 4 + e;
                outp[(size_t)m * D_ + n] = acc[i][j][e] + bv;
            }
        }
}

// ---- fused causal attention v13: R15 + coalesced writer stores ----
// Phase 1: R15-exact. Phase 2: barrier-free direct-global-K streaming, but each
// kt tile is repacked through wave-private LDS (aliases V_lds, XOR-swizzled) so
// each NT store instruction covers 4 rows x 256B contiguous (vs 16 x 64B).
__global__ __launch_bounds__(256, 4) void k_attn(const bf16_t* __restrict__ Q,
                                                 const bf16_t* __restrict__ Kb,
                                                 const bf16_t* __restrict__ VT,
                                                 bf16_t* __restrict__ ctx,
                                                 float* __restrict__ attn) {
    __shared__ __align__(16) bf16_t K_lds[2][64][64];
    __shared__ __align__(16) bf16_t V_lds[2][64][64];
    int tid = threadIdx.x, lane = tid & 63, wid = tid >> 6;
    int bid = blockIdx.x;
    int r   = bid >> 3;                    // 0..127
    int jj  = r & 31, s = r >> 5;          // CU-slot j, head-group s
    int bh  = (bid & 7) + 8 * s;           // 4 heads per XCD
    int j2  = (jj + ((s >> 1) << 4)) & 31;
    int qt  = (s & 1) ? (31 - j2) : j2;    // balanced involution
    int b = bh >> 4, h = bh & 15;
    int qb = qt * 64;
    const int diag = qt;                   // 64-key strips 0..diag
    const bf16_t* Qh = Q  + (size_t)bh * L_ * HD_;
    const bf16_t* Kh = Kb + (size_t)bh * L_ * HD_;
    const bf16_t* Vh = VT + (size_t)bh * HD_ * L_;
    int r16 = lane & 15, g = lane >> 4;
    const float scale2 = 0.125f * 1.44269504088896340736f;
    const float clamp2 = 50.0f * 1.44269504088896340736f;
    int qrow0 = qb + wid * 16;
    int qrow  = qrow0 + r16;               // this lane's q-row (score col)

    // zero-fill upper triangle FIRST: fire-and-forget NT stores
    {
        int zs = qb + 64;
        f32x4 z4 = {0.f, 0.f, 0.f, 0.f};
        for (int rr = 0; rr < 16; ++rr) {
            float* rowp = attn + ((size_t)bh * L_ + qrow0 + rr) * L_;
            for (int c = zs + lane * 4; c < L_; c += 256)
                __builtin_nontemporal_store(z4, (f32x4*)&rowp[c]);
        }
    }

    bf16x8 q0 = *(const bf16x8*)&Qh[(size_t)qrow * HD_ + g * 8];
    bf16x8 q1 = *(const bf16x8*)&Qh[(size_t)qrow * HD_ + 32 + g * 8];

    // staging: 8 rows x 128B per gl16; source XOR-swizzled (unit ^= row&7), LDS linear
    int srow = lane >> 3, sunit = ((lane & 7) ^ (lane >> 3)) * 8;
    auto STAGE_K = [&](int kt1, int nxt) {
        #pragma unroll
        for (int i = 0; i < 2; ++i) {
            int cb = wid * 16 + i * 8;
            gl16(&Kh[(size_t)(kt1 * 64 + cb + srow) * HD_ + sunit], &K_lds[nxt][cb][0]);
        }
    };
    auto STAGE_V = [&](int kt1, int nxt) {
        #pragma unroll
        for (int i = 0; i < 2; ++i) {
            int cb = wid * 16 + i * 8;
            gl16(&Vh[(size_t)(cb + srow) * L_ + kt1 * 64 + sunit], &V_lds[nxt][cb][0]);
        }
    };

    f32x4 ctxa[4] = {};
    float zsum = 0.f;
    int rx = r16 & 7;

    // ---- phase 1: Z + unnormalized PV (LDS-staged, barriers) ----
    STAGE_K(0, 0); STAGE_V(0, 0);
    int cur = 0;
    for (int kt = 0; kt <= diag; ++kt) {
        __syncthreads();
        int nxt = cur ^ 1;
        if (kt < diag) { STAGE_K(kt + 1, nxt); STAGE_V(kt + 1, nxt); }
        int kb = kt * 64;
        #pragma unroll
        for (int sub = 0; sub < 2; ++sub) {
            f32x4 sa[2];
            #pragma unroll
            for (int sp = 0; sp < 2; ++sp) {
                int krow = sub * 32 + sp * 16 + r16;
                bf16x8 kf0 = *(const bf16x8*)&K_lds[cur][krow][(g ^ rx) * 8];
                bf16x8 kf1 = *(const bf16x8*)&K_lds[cur][krow][((4 + g) ^ rx) * 8];
                f32x4 zz = {};
                sa[sp] = mfma16(kf1, q1, mfma16(kf0, q0, zz));
            }
            int kb2 = kb + sub * 32;
            u32 dw[2][2];
            #pragma unroll
            for (int sp = 0; sp < 2; ++sp) {
                float ev[4];
                #pragma unroll
                for (int e = 0; e < 4; ++e) {
                    int key = kb2 + sp * 16 + g * 4 + e;
                    float sc = fminf(fmaxf(sa[sp][e] * scale2, -clamp2), clamp2);
                    ev[e] = (key > qrow) ? 0.f : exp2f(sc);
                    zsum += ev[e];
                }
                dw[sp][0] = cvtpk(ev[0], ev[1]);
                dw[sp][1] = cvtpk(ev[2], ev[3]);
            }
            union { u32 u[4]; bf16x8 v; } pa;
            pa.u[0] = dw[0][0]; pa.u[1] = dw[0][1];
            pa.u[2] = dw[1][0]; pa.u[3] = dw[1][1];
            #pragma unroll
            for (int t = 0; t < 4; ++t) {
                int vrow = t * 16 + r16;
                int u0 = ((sub * 4 + (g >> 1)) ^ rx) * 8 + (g & 1) * 4;
                int u1 = ((sub * 4 + 2 + (g >> 1)) ^ rx) * 8 + (g & 1) * 4;
                union { u64 d[2]; bf16x8 v; } vf;
                vf.d[0] = *(const u64*)&V_lds[cur][vrow][u0];
                vf.d[1] = *(const u64*)&V_lds[cur][vrow][u1];
                ctxa[t] = mfma16(pa.v, vf.v, ctxa[t]);
            }
        }
        cur = nxt;
    }

    float v = zsum;
    v += __shfl_xor(v, 16);
    v += __shfl_xor(v, 32);
    float invz = 1.f / v;

    // normalized context -> ctx [B, L, D] bf16 (PV D: row=g*4+e=q, col=r16=hd)
    #pragma unroll
    for (int e = 0; e < 4; ++e) {
        float izq = __shfl(invz, g * 4 + e);
        int qr = qrow0 + g * 4 + e;
        #pragma unroll
        for (int t = 0; t < 4; ++t)
            ctx[((size_t)b * L_ + qr) * D_ + h * HD_ + t * 16 + r16] =
                __float2bfloat16(ctxa[t][e] * izq);
    }

    // ---- phase 2: barrier-free streaming with LDS-repacked coalesced stores ----
    __syncthreads();    // all waves done with V_lds before wave-private reuse
    // wave-private 16 rows x 64 cols f32 scratch, aliases V_lds (4 KB per wave)
    float* pw = (float*)&V_lds[0][0][0] + wid * 1024;
    int rs = lane >> 4;                    // 0..3  (store row-subgroup)
    int cc = lane & 15;                    // 0..15 (store col unit)
    for (int kt = 0; kt <= diag; ++kt) {
        #pragma unroll
        for (int sub = 0; sub < 2; ++sub) {
            int krow0 = kt * 64 + sub * 32;
            #pragma unroll
            for (int sp = 0; sp < 2; ++sp) {
                const bf16_t* kp = &Kh[(size_t)(krow0 + sp * 16 + r16) * HD_ + g * 8];
                bf16x8 kf0 = *(const bf16x8*)kp;
                bf16x8 kf1 = *(const bf16x8*)(kp + 32);
                f32x4 zz = {};
                f32x4 sa = mfma16(kf1, q1, mfma16(kf0, q0, zz));
                int cb = krow0 + sp * 16 + g * 4;
                f32x4 fv;
                #pragma unroll
                for (int e = 0; e < 4; ++e) {
                    int key = cb + e;
                    float sc = fminf(fmaxf(sa[e] * scale2, -clamp2), clamp2);
                    fv[e] = (key > qrow) ? 0.f : exp2f(sc) * invz;
                }
                // LDS repack: logical unit = sub*8+sp*4+g, XOR-swizzled by row parity
                int un = (sub * 8 + sp * 4 + g) ^ ((r16 & 1) * 4);
                *(f32x4*)&pw[r16 * 64 + un * 4] = fv;
            }
        }
        // transposed coalesced NT stores: 4 instrs, each 4 rows x 256B contiguous
        #pragma unroll
        for (int j4 = 0; j4 < 4; ++j4) {
            int row = j4 * 4 + rs;
            int un = cc ^ ((rs & 1) * 4);
            f32x4 t = *(const f32x4*)&pw[row * 64 + un * 4];
            __builtin_nontemporal_store(t,
                (f32x4*)&attn[((size_t)bh * L_ + qrow0 + row) * L_ + kt * 64 + cc * 4]);
        }
    }
}

extern "C" void kernel_launch(void* const* d_in, const int* in_sizes, int n_in,
                              void* d_out, int out_size, void* d_ws, size_t ws_size,
                              hipStream_t stream) {
    const float* x  = (const float*)d_in[0];
    const float* wq = (const float*)d_in[1];
    const float* bq = (const float*)d_in[2];
    const float* wk = (const float*)d_in[3];
    const float* bk = (const float*)d_in[4];
    const float* wv = (const float*)d_in[5];
    const float* bv = (const float*)d_in[6];
    const float* wo = (const float*)d_in[7];
    const float* bo = (const float*)d_in[8];

    char* ws = (char*)d_ws;
    bf16_t* xb   = (bf16_t*)(ws);
    bf16_t* wqt  = (bf16_t*)(ws + ( 8u << 20));
    bf16_t* wkt  = (bf16_t*)(ws + (10u << 20));
    bf16_t* wvt  = (bf16_t*)(ws + (12u << 20));
    bf16_t* wot  = (bf16_t*)(ws + (14u << 20));
    bf16_t* Qb   = (bf16_t*)(ws + (16u << 20));
    bf16_t* Kbuf = (bf16_t*)(ws + (24u << 20));
    bf16_t* VTb  = (bf16_t*)(ws + (32u << 20));
    bf16_t* ctxb = (bf16_t*)(ws + (40u << 20));

    float* out  = (float*)d_out;
    float* attn = out + (size_t)B_ * L_ * D_;

    dim3 gp(16, 16, 12);
    k_prep<<<gp, 256, 0, stream>>>(x, wq, wk, wv, wo, xb, wqt, wkt, wvt, wot);

    dim3 g3(D_ / 128, (B_ * L_) / 128, 3);
    k_gemm_qkv<<<g3, 256, 0, stream>>>(xb, wqt, wkt, wvt, bq, bk, bv, Qb, Kbuf, VTb);

    k_attn<<<1024, 256, 0, stream>>>(Qb, Kbuf, VTb, ctxb, attn);

    dim3 gg(D_ / 64, (B_ * L_) / 128);
    k_gemm_o<<<gg, 256, 0, stream>>>(ctxb, wot, bo, (float*)d_out);
}

// Round 19
// 218.865 us; speedup vs baseline: 1.1605x; 1.0091x over previous
//
#include <hip/hip_runtime.h>
#include <hip/hip_bf16.h>

#define B_  2
#define L_  2048
#define D_  1024
#define H_  16
#define HD_ 64

typedef __bf16 bf16x8 __attribute__((ext_vector_type(8)));
typedef float  f32x4  __attribute__((ext_vector_type(4)));
using bf16_t = __hip_bfloat16;
typedef unsigned int u32;
typedef unsigned long long u64;

static __device__ __forceinline__ f32x4 mfma16(bf16x8 a, bf16x8 b, f32x4 c) {
    return __builtin_amdgcn_mfma_f32_16x16x32_bf16(a, b, c, 0, 0, 0);
}

// async global->LDS, 16B per lane; LDS dest = wave-uniform base + lane*16
static __device__ __forceinline__ void gl16(const bf16_t* g, bf16_t* l) {
    __builtin_amdgcn_global_load_lds(
        (const __attribute__((address_space(1))) unsigned int*)g,
        (__attribute__((address_space(3))) unsigned int*)l, 16, 0, 0);
}

// packed f32x2 -> bf16x2 (lo in low half)
static __device__ __forceinline__ u32 cvtpk(float lo, float hi) {
    u32 r;
    asm("v_cvt_pk_bf16_f32 %0, %1, %2" : "=v"(r) : "v"(lo), "v"(hi));
    return r;
}

// ---- prep: z<4 -> transpose W[k][n] to bf16 Wt[n][k]; z>=4 -> convert x to bf16 ----
__global__ __launch_bounds__(256) void k_prep(
        const float* __restrict__ x,
        const float* __restrict__ w0, const float* __restrict__ w1,
        const float* __restrict__ w2, const float* __restrict__ w3,
        bf16_t* __restrict__ xb,
        bf16_t* __restrict__ t0, bf16_t* __restrict__ t1,
        bf16_t* __restrict__ t2, bf16_t* __restrict__ t3) {
    __shared__ bf16_t tile[64][65];
    int z = blockIdx.z;
    int t = threadIdx.x;
    if (z >= 4) {
        int slice = z - 4;                              // 0..7
        int lin = blockIdx.y * 16 + blockIdx.x;         // 0..255
        int idx = (slice * 256 + lin) * 256 + t;        // 0..524287
        const float4* p = (const float4*)x + (size_t)idx * 2;
        float4 a = p[0], b = p[1];
        union { bf16_t h[8]; bf16x8 v; } u;
        u.h[0] = __float2bfloat16(a.x); u.h[1] = __float2bfloat16(a.y);
        u.h[2] = __float2bfloat16(a.z); u.h[3] = __float2bfloat16(a.w);
        u.h[4] = __float2bfloat16(b.x); u.h[5] = __float2bfloat16(b.y);
        u.h[6] = __float2bfloat16(b.z); u.h[7] = __float2bfloat16(b.w);
        *(bf16x8*)(xb + (size_t)idx * 8) = u.v;
        return;
    }
    const float* w = (z == 0) ? w0 : (z == 1) ? w1 : (z == 2) ? w2 : w3;
    bf16_t* wt     = (z == 0) ? t0 : (z == 1) ? t1 : (z == 2) ? t2 : t3;
    int kb = blockIdx.x * 64, nb = blockIdx.y * 64;
    int r  = t >> 4, c4 = (t & 15) * 4;
    #pragma unroll
    for (int it = 0; it < 4; ++it) {
        int kr = r + it * 16;
        float4 v = *(const float4*)&w[(size_t)(kb + kr) * D_ + nb + c4];
        tile[kr][c4 + 0] = __float2bfloat16(v.x);
        tile[kr][c4 + 1] = __float2bfloat16(v.y);
        tile[kr][c4 + 2] = __float2bfloat16(v.z);
        tile[kr][c4 + 3] = __float2bfloat16(v.w);
    }
    __syncthreads();
    #pragma unroll
    for (int it = 0; it < 4; ++it) {
        int nr = r + it * 16;
        union { bf16_t h[4]; u64 u; } o;
        o.h[0] = tile[c4 + 0][nr];
        o.h[1] = tile[c4 + 1][nr];
        o.h[2] = tile[c4 + 2][nr];
        o.h[3] = tile[c4 + 3][nr];
        *(u64*)&wt[(size_t)(nb + nr) * D_ + kb + c4] = o.u;
    }
}

// ---- merged QKV GEMM: z=0 -> Q [B,H,L,HD], z=1 -> K [B,H,L,HD], z=2 -> V^T [B,H,HD,L]
__global__ __launch_bounds__(256, 3) void k_gemm_qkv(
        const bf16_t* __restrict__ A,
        const bf16_t* __restrict__ Wq, const bf16_t* __restrict__ Wk, const bf16_t* __restrict__ Wv,
        const float* __restrict__ bq, const float* __restrict__ bk, const float* __restrict__ bv,
        bf16_t* __restrict__ Qo, bf16_t* __restrict__ Ko, bf16_t* __restrict__ Vo) {
    __shared__ __align__(16) bf16_t Al[128][32];
    __shared__ __align__(16) bf16_t Bl[128][32];
    const int K = D_;
    int z = blockIdx.z;
    const bf16_t* Wt = (z == 0) ? Wq : (z == 1) ? Wk : Wv;
    const float* bias = (z == 0) ? bq : (z == 1) ? bk : bv;
    bf16_t* outp      = (z == 0) ? Qo : (z == 1) ? Ko : Vo;
    int tid = threadIdx.x, lane = tid & 63, wid = tid >> 6;
    int m0 = blockIdx.y * 128, n0 = blockIdx.x * 128;
    int wm = (wid >> 1) * 64, wn = (wid & 1) * 64;
    int r16 = lane & 15, g = lane >> 4;
    int lrow = lane >> 2, lcol = (lane & 3) * 8;
    f32x4 acc[4][4] = {};
    for (int kb = 0; kb < K; kb += 32) {
        __syncthreads();
        gl16(&A [(size_t)(m0 + wid * 32 + lrow) * K + kb + lcol],      &Al[wid * 32][0]);
        gl16(&A [(size_t)(m0 + wid * 32 + 16 + lrow) * K + kb + lcol], &Al[wid * 32 + 16][0]);
        gl16(&Wt[(size_t)(n0 + wid * 32 + lrow) * K + kb + lcol],      &Bl[wid * 32][0]);
        gl16(&Wt[(size_t)(n0 + wid * 32 + 16 + lrow) * K + kb + lcol], &Bl[wid * 32 + 16][0]);
        __syncthreads();
        bf16x8 af[4], bfr[4];
        #pragma unroll
        for (int i = 0; i < 4; ++i) af[i]  = *(const bf16x8*)&Al[wm + i * 16 + r16][g * 8];
        #pragma unroll
        for (int j = 0; j < 4; ++j) bfr[j] = *(const bf16x8*)&Bl[wn + j * 16 + r16][g * 8];
        #pragma unroll
        for (int i = 0; i < 4; ++i)
            #pragma unroll
            for (int j = 0; j < 4; ++j)
                acc[i][j] = mfma16(af[i], bfr[j], acc[i][j]);
    }
    if (z == 2) {
        #pragma unroll
        for (int i = 0; i < 4; ++i)
            #pragma unroll
            for (int j = 0; j < 4; ++j) {
                int n = n0 + wn + j * 16 + r16;
                float bv2 = bias[n];
                int h = n >> 6, hd = n & 63;
                int m = m0 + wm + i * 16 + g * 4;
                int bb = m >> 11, l0 = m & (L_ - 1);
                u32 lo = cvtpk(acc[i][j][0] + bv2, acc[i][j][1] + bv2);
                u32 hi = cvtpk(acc[i][j][2] + bv2, acc[i][j][3] + bv2);
                u64 pk = ((u64)hi << 32) | lo;
                *(u64*)&Vo[(((size_t)(bb * H_ + h)) * HD_ + hd) * L_ + l0] = pk;
            }
    } else {
        #pragma unroll
        for (int i = 0; i < 4; ++i) {
            #pragma unroll
            for (int j = 0; j < 4; ++j) {
                int n = n0 + wn + j * 16 + r16;
                float bv2 = bias[n];
                int h = n >> 6, hd = n & 63;
                #pragma unroll
                for (int e = 0; e < 4; ++e) {
                    int m = m0 + wm + i * 16 + g * 4 + e;
                    float v = acc[i][j][e] + bv2;
                    int bb = m >> 11, l = m & (L_ - 1);
                    outp[(((size_t)(bb * H_ + h)) * L_ + l) * HD_ + hd] = __float2bfloat16(v);
                }
            }
        }
    }
}

// ---- O-projection GEMM, 128x64 tiles ----
__global__ __launch_bounds__(256, 2) void k_gemm_o(const bf16_t* __restrict__ A,
                                                   const bf16_t* __restrict__ Wt,
                                                   const float* __restrict__ bias,
                                                   float* __restrict__ outp) {
    __shared__ __align__(16) bf16_t Al[128][32];
    __shared__ __align__(16) bf16_t Bl[64][32];
    const int K = D_;
    int tid = threadIdx.x, lane = tid & 63, wid = tid >> 6;
    int m0 = blockIdx.y * 128, n0 = blockIdx.x * 64;
    int wm = (wid >> 1) * 64, wn = (wid & 1) * 32;
    int r16 = lane & 15, g = lane >> 4;
    int lrow = lane >> 2, lcol = (lane & 3) * 8;
    f32x4 acc[4][2] = {};
    for (int kb = 0; kb < K; kb += 32) {
        __syncthreads();
        gl16(&A [(size_t)(m0 + wid * 32 + lrow) * K + kb + lcol],      &Al[wid * 32][0]);
        gl16(&A [(size_t)(m0 + wid * 32 + 16 + lrow) * K + kb + lcol], &Al[wid * 32 + 16][0]);
        gl16(&Wt[(size_t)(n0 + wid * 16 + lrow) * K + kb + lcol],      &Bl[wid * 16][0]);
        __syncthreads();
        bf16x8 af[4], bfr[2];
        #pragma unroll
        for (int i = 0; i < 4; ++i) af[i]  = *(const bf16x8*)&Al[wm + i * 16 + r16][g * 8];
        #pragma unroll
        for (int j = 0; j < 2; ++j) bfr[j] = *(const bf16x8*)&Bl[wn + j * 16 + r16][g * 8];
        #pragma unroll
        for (int i = 0; i < 4; ++i)
            #pragma unroll
            for (int j = 0; j < 2; ++j)
                acc[i][j] = mfma16(af[i], bfr[j], acc[i][j]);
    }
    #pragma unroll
    for (int i = 0; i < 4; ++i)
        #pragma unroll
        for (int j = 0; j < 2; ++j) {
            int n = n0 + wn + j * 16 + r16;
            float bv = bias[n];
            #pragma unroll
            for (int e = 0; e < 4; ++e) {
                int m = m0 + wm + i * 16 + g * 4 + e;
                outp[(size_t)m * D_ + n] = acc[i][j][e] + bv;
            }
        }
}

// ---- fused causal attention v14: R18 structure at 5 blocks/CU ----
// LDS = exactly 32 KB -> 5 blocks/CU fit; __launch_bounds__(256,5) caps VGPRs
// at ~102 so the allocator doesn't block the 5th block. +25% waves/CU for
// store/load latency hiding. Everything else byte-identical to R18.
__global__ __launch_bounds__(256, 5) void k_attn(const bf16_t* __restrict__ Q,
                                                 const bf16_t* __restrict__ Kb,
                                                 const bf16_t* __restrict__ VT,
                                                 bf16_t* __restrict__ ctx,
                                                 float* __restrict__ attn) {
    __shared__ __align__(16) bf16_t K_lds[2][64][64];
    __shared__ __align__(16) bf16_t V_lds[2][64][64];
    int tid = threadIdx.x, lane = tid & 63, wid = tid >> 6;
    int bid = blockIdx.x;
    int r   = bid >> 3;                    // 0..127
    int jj  = r & 31, s = r >> 5;          // CU-slot j, head-group s
    int bh  = (bid & 7) + 8 * s;           // 4 heads per XCD
    int j2  = (jj + ((s >> 1) << 4)) & 31;
    int qt  = (s & 1) ? (31 - j2) : j2;    // balanced involution
    int b = bh >> 4, h = bh & 15;
    int qb = qt * 64;
    const int diag = qt;                   // 64-key strips 0..diag
    const bf16_t* Qh = Q  + (size_t)bh * L_ * HD_;
    const bf16_t* Kh = Kb + (size_t)bh * L_ * HD_;
    const bf16_t* Vh = VT + (size_t)bh * HD_ * L_;
    int r16 = lane & 15, g = lane >> 4;
    const float scale2 = 0.125f * 1.44269504088896340736f;
    const float clamp2 = 50.0f * 1.44269504088896340736f;
    int qrow0 = qb + wid * 16;
    int qrow  = qrow0 + r16;               // this lane's q-row (score col)

    // zero-fill upper triangle FIRST: fire-and-forget NT stores
    {
        int zs = qb + 64;
        f32x4 z4 = {0.f, 0.f, 0.f, 0.f};
        for (int rr = 0; rr < 16; ++rr) {
            float* rowp = attn + ((size_t)bh * L_ + qrow0 + rr) * L_;
            for (int c = zs + lane * 4; c < L_; c += 256)
                __builtin_nontemporal_store(z4, (f32x4*)&rowp[c]);
        }
    }

    bf16x8 q0 = *(const bf16x8*)&Qh[(size_t)qrow * HD_ + g * 8];
    bf16x8 q1 = *(const bf16x8*)&Qh[(size_t)qrow * HD_ + 32 + g * 8];

    // staging: 8 rows x 128B per gl16; source XOR-swizzled (unit ^= row&7), LDS linear
    int srow = lane >> 3, sunit = ((lane & 7) ^ (lane >> 3)) * 8;
    auto STAGE_K = [&](int kt1, int nxt) {
        #pragma unroll
        for (int i = 0; i < 2; ++i) {
            int cb = wid * 16 + i * 8;
            gl16(&Kh[(size_t)(kt1 * 64 + cb + srow) * HD_ + sunit], &K_lds[nxt][cb][0]);
        }
    };
    auto STAGE_V = [&](int kt1, int nxt) {
        #pragma unroll
        for (int i = 0; i < 2; ++i) {
            int cb = wid * 16 + i * 8;
            gl16(&Vh[(size_t)(cb + srow) * L_ + kt1 * 64 + sunit], &V_lds[nxt][cb][0]);
        }
    };

    f32x4 ctxa[4] = {};
    float zsum = 0.f;
    int rx = r16 & 7;

    // ---- phase 1: Z + unnormalized PV (LDS-staged, barriers) ----
    STAGE_K(0, 0); STAGE_V(0, 0);
    int cur = 0;
    for (int kt = 0; kt <= diag; ++kt) {
        __syncthreads();
        int nxt = cur ^ 1;
        if (kt < diag) { STAGE_K(kt + 1, nxt); STAGE_V(kt + 1, nxt); }
        int kb = kt * 64;
        #pragma unroll
        for (int sub = 0; sub < 2; ++sub) {
            f32x4 sa[2];
            #pragma unroll
            for (int sp = 0; sp < 2; ++sp) {
                int krow = sub * 32 + sp * 16 + r16;
                bf16x8 kf0 = *(const bf16x8*)&K_lds[cur][krow][(g ^ rx) * 8];
                bf16x8 kf1 = *(const bf16x8*)&K_lds[cur][krow][((4 + g) ^ rx) * 8];
                f32x4 zz = {};
                sa[sp] = mfma16(kf1, q1, mfma16(kf0, q0, zz));
            }
            int kb2 = kb + sub * 32;
            u32 dw[2][2];
            #pragma unroll
            for (int sp = 0; sp < 2; ++sp) {
                float ev[4];
                #pragma unroll
                for (int e = 0; e < 4; ++e) {
                    int key = kb2 + sp * 16 + g * 4 + e;
                    float sc = fminf(fmaxf(sa[sp][e] * scale2, -clamp2), clamp2);
                    ev[e] = (key > qrow) ? 0.f : exp2f(sc);
                    zsum += ev[e];
                }
                dw[sp][0] = cvtpk(ev[0], ev[1]);
                dw[sp][1] = cvtpk(ev[2], ev[3]);
            }
            union { u32 u[4]; bf16x8 v; } pa;
            pa.u[0] = dw[0][0]; pa.u[1] = dw[0][1];
            pa.u[2] = dw[1][0]; pa.u[3] = dw[1][1];
            #pragma unroll
            for (int t = 0; t < 4; ++t) {
                int vrow = t * 16 + r16;
                int u0 = ((sub * 4 + (g >> 1)) ^ rx) * 8 + (g & 1) * 4;
                int u1 = ((sub * 4 + 2 + (g >> 1)) ^ rx) * 8 + (g & 1) * 4;
                union { u64 d[2]; bf16x8 v; } vf;
                vf.d[0] = *(const u64*)&V_lds[cur][vrow][u0];
                vf.d[1] = *(const u64*)&V_lds[cur][vrow][u1];
                ctxa[t] = mfma16(pa.v, vf.v, ctxa[t]);
            }
        }
        cur = nxt;
    }

    float v = zsum;
    v += __shfl_xor(v, 16);
    v += __shfl_xor(v, 32);
    float invz = 1.f / v;

    // normalized context -> ctx [B, L, D] bf16 (PV D: row=g*4+e=q, col=r16=hd)
    #pragma unroll
    for (int e = 0; e < 4; ++e) {
        float izq = __shfl(invz, g * 4 + e);
        int qr = qrow0 + g * 4 + e;
        #pragma unroll
        for (int t = 0; t < 4; ++t)
            ctx[((size_t)b * L_ + qr) * D_ + h * HD_ + t * 16 + r16] =
                __float2bfloat16(ctxa[t][e] * izq);
    }

    // ---- phase 2: barrier-free streaming with LDS-repacked coalesced stores ----
    __syncthreads();    // all waves done with V_lds before wave-private reuse
    // wave-private 16 rows x 64 cols f32 scratch, aliases V_lds (4 KB per wave)
    float* pw = (float*)&V_lds[0][0][0] + wid * 1024;
    int rs = lane >> 4;                    // 0..3  (store row-subgroup)
    int cc = lane & 15;                    // 0..15 (store col unit)
    for (int kt = 0; kt <= diag; ++kt) {
        #pragma unroll
        for (int sub = 0; sub < 2; ++sub) {
            int krow0 = kt * 64 + sub * 32;
            #pragma unroll
            for (int sp = 0; sp < 2; ++sp) {
                const bf16_t* kp = &Kh[(size_t)(krow0 + sp * 16 + r16) * HD_ + g * 8];
                bf16x8 kf0 = *(const bf16x8*)kp;
                bf16x8 kf1 = *(const bf16x8*)(kp + 32);
                f32x4 zz = {};
                f32x4 sa = mfma16(kf1, q1, mfma16(kf0, q0, zz));
                int cb = krow0 + sp * 16 + g * 4;
                f32x4 fv;
                #pragma unroll
                for (int e = 0; e < 4; ++e) {
                    int key = cb + e;
                    float sc = fminf(fmaxf(sa[e] * scale2, -clamp2), clamp2);
                    fv[e] = (key > qrow) ? 0.f : exp2f(sc) * invz;
                }
                // LDS repack: logical unit = sub*8+sp*4+g, XOR-swizzled by row parity
                int un = (sub * 8 + sp * 4 + g) ^ ((r16 & 1) * 4);
                *(f32x4*)&pw[r16 * 64 + un * 4] = fv;
            }
        }
        // transposed coalesced NT stores: 4 instrs, each 4 rows x 256B contiguous
        #pragma unroll
        for (int j4 = 0; j4 < 4; ++j4) {
            int row = j4 * 4 + rs;
            int un = cc ^ ((rs & 1) * 4);
            f32x4 t = *(const f32x4*)&pw[row * 64 + un * 4];
            __builtin_nontemporal_store(t,
                (f32x4*)&attn[((size_t)bh * L_ + qrow0 + row) * L_ + kt * 64 + cc * 4]);
        }
    }
}

extern "C" void kernel_launch(void* const* d_in, const int* in_sizes, int n_in,
                              void* d_out, int out_size, void* d_ws, size_t ws_size,
                              hipStream_t stream) {
    const float* x  = (const float*)d_in[0];
    const float* wq = (const float*)d_in[1];
    const float* bq = (const float*)d_in[2];
    const float* wk = (const float*)d_in[3];
    const float* bk = (const float*)d_in[4];
    const float* wv = (const float*)d_in[5];
    const float* bv = (const float*)d_in[6];
    const float* wo = (const float*)d_in[7];
    const float* bo = (const float*)d_in[8];

    char* ws = (char*)d_ws;
    bf16_t* xb   = (bf16_t*)(ws);
    bf16_t* wqt  = (bf16_t*)(ws + ( 8u << 20));
    bf16_t* wkt  = (bf16_t*)(ws + (10u << 20));
    bf16_t* wvt  = (bf16_t*)(ws + (12u << 20));
    bf16_t* wot  = (bf16_t*)(ws + (14u << 20));
    bf16_t* Qb   = (bf16_t*)(ws + (16u << 20));
    bf16_t* Kbuf = (bf16_t*)(ws + (24u << 20));
    bf16_t* VTb  = (bf16_t*)(ws + (32u << 20));
    bf16_t* ctxb = (bf16_t*)(ws + (40u << 20));

    float* out  = (float*)d_out;
    float* attn = out + (size_t)B_ * L_ * D_;

    dim3 gp(16, 16, 12);
    k_prep<<<gp, 256, 0, stream>>>(x, wq, wk, wv, wo, xb, wqt, wkt, wvt, wot);

    dim3 g3(D_ / 128, (B_ * L_) / 128, 3);
    k_gemm_qkv<<<g3, 256, 0, stream>>>(xb, wqt, wkt, wvt, bq, bk, bv, Qb, Kbuf, VTb);

    k_attn<<<1024, 256, 0, stream>>>(Qb, Kbuf, VTb, ctxb, attn);

    dim3 gg(D_ / 64, (B_ * L_) / 128);
    k_gemm_o<<<gg, 256, 0, stream>>>(ctxb, wot, bo, (float*)d_out);
}